// Round 1
// baseline (209.617 us; speedup 1.0000x reference)
//
#include <hip/hip_runtime.h>
#include <math.h>

// Problem constants (match the jax reference)
constexpr int B_  = 2;
constexpr int C_  = 64;
constexpr int HW_ = 64 * 128;      // 8192
constexpr int N_  = HW_;           // points per image (near == far == 8192)
constexpr int NX_ = 512;
constexpr int NY_ = 512;
constexpr int NYNX_ = NX_ * NY_;   // 262144
constexpr int GC_  = 32;           // NN search grid is GC x GC cells of 1.6 m
constexpr int GCC_ = GC_ * GC_;    // 1024 cells
constexpr int LPF_ = 8;            // lanes per far point in nn_search
constexpr int BN_  = B_ * N_;      // 16384
constexpr int NNB_ = BN_ / (256 / LPF_);   // 512 NN blocks (32 far pts/block)
constexpr int ZB_  = 8;            // zero-list blocks in build_grid

typedef float vf4 __attribute__((ext_vector_type(4)));
__device__ __forceinline__ void store_nt(float4* p, float4 v) {
  vf4 t = {v.x, v.y, v.z, v.w};
  __builtin_nontemporal_store(t, (vf4*)p);
}

// ---------------------------------------------------------------------------
// Shared voxel binning (numpy f32 bitwise). -1 = contributes nothing.
// ---------------------------------------------------------------------------
__device__ __forceinline__ int voxel_of(float x, float y, float w) {
#pragma clang fp contract(off)
  if (w == 0.0f) return -1;
  float qx = (x - 0.0f) / 0.1f;
  float qy = (y - (-25.6f)) / 0.1f;
  int ix = (int)floorf(qx);
  int iy = (int)floorf(qy);
  if (ix < 0 || ix >= NX_ || iy < 0 || iy >= NY_) return -1;
  return iy * NX_ + ix;
}

// NN-grid cell coords (internal only — must be identical in build & search).
__device__ __forceinline__ int gcell_x(float x) {
  int c = (int)floorf(x * 0.625f);          // /1.6
  return min(GC_ - 1, max(0, c));
}
__device__ __forceinline__ int gcell_y(float y) {
  int c = (int)floorf((y + 25.6f) * 0.625f);
  return min(GC_ - 1, max(0, c));
}

// ---------------------------------------------------------------------------
// Fused prep: blocks [0,64) pack+count points AND build the per-batch NN-cell
// histogram. NEW: the cnt atomics detect the 1->2 transition (atomicAdd
// returns old) and append that voxel to vlist exactly once — this replaces
// build_grid's 2048-block scan of the full 2 MB cnt array.
// Blocks [64,320) transpose fv (B,C,HW) -> fvT (B,HW,C). Halves independent.
// ---------------------------------------------------------------------------
__global__ __launch_bounds__(256) void prep_kernel(
    const float* __restrict__ fv,
    const float* __restrict__ pi, const int* __restrict__ pm,
    const float* __restrict__ pif, const int* __restrict__ pmf,
    float4* __restrict__ near4, float4* __restrict__ far4,
    float4* __restrict__ nearnn, float* __restrict__ cnt,
    int* __restrict__ gcellcnt, int* __restrict__ pcell,
    int* __restrict__ vcur, int* __restrict__ vlist,
    float* __restrict__ fvT) {
#pragma clang fp contract(off)
  __shared__ float tile[64][65];
  if (blockIdx.x < 64) {
    // ---- pack + count + cell histogram ----
    int t = blockIdx.x * 256 + threadIdx.x;        // over B_*N_
    int k = t / N_, n = t % N_;
    const float* base  = pi  + (size_t)k * 4 * HW_;
    const float* basef = pif + (size_t)k * 4 * HW_;
    float x = base[n], y = base[HW_ + n], z = base[2 * HW_ + n];
    bool v = pm[k * HW_ + n] > 0;
    near4[t] = make_float4(x, y, z, v ? 1.0f : 0.0f);
    float sq = (x * x + y * y) + z * z;   // numpy 3-elem sum order
    nearnn[t] = v ? make_float4(x, y, z, sq)
                 : make_float4(0.0f, 0.0f, 0.0f, 1e10f);
    float fx = basef[n], fy = basef[HW_ + n], fz = basef[2 * HW_ + n];
    bool vf = pmf[k * HW_ + n] > 0;
    far4[t] = make_float4(fx, fy, fz, vf ? 1.0f : 0.0f);

    // NN-cell id for valid near points (-1 masked) + histogram
    if (v) {
      int c = gcell_y(y) * GC_ + gcell_x(x);
      pcell[t] = c;
      atomicAdd(&gcellcnt[k * GCC_ + c], 1);
    } else {
      pcell[t] = -1;
    }

    int vn = voxel_of(x, y, v ? 1.0f : 0.0f);
    if (vn >= 0) {
      float old = atomicAdd(&cnt[(size_t)k * NYNX_ + vn], 1.0f);
      if (old == 1.0f) {            // exactly one thread sees the 1->2 step
        int p = atomicAdd(vcur, 1);
        vlist[p] = k * NYNX_ + vn;
      }
    }
    int vfv = voxel_of(fx, fy, vf ? 1.0f : 0.0f);
    if (vfv >= 0) {
      float old2 = atomicAdd(&cnt[(size_t)k * NYNX_ + vfv], 1.0f);
      if (old2 == 1.0f) {
        int p = atomicAdd(vcur, 1);
        vlist[p] = k * NYNX_ + vfv;
      }
    }
  } else {
    // ---- transpose ----
    int bid = blockIdx.x - 64;          // 0..255
    int k = bid >> 7;                   // /128
    int n0 = (bid & 127) * 64;
    int tx = threadIdx.x & 63, ty = threadIdx.x >> 6;
    for (int c = ty; c < C_; c += 4)
      tile[c][tx] = fv[((size_t)(k * C_ + c)) * HW_ + n0 + tx];
    __syncthreads();
    for (int nn = ty; nn < 64; nn += 4)
      fvT[((size_t)(k * HW_ + n0 + nn)) * C_ + tx] = tile[tx][nn];
  }
}

// ---------------------------------------------------------------------------
// Lexicographic stable top-3 insert on (value, index): lower value wins,
// ties broken by lower index. Order-INDEPENDENT (safe for arbitrary candidate
// order) and equal to jax stable top-k. Invariant: slots lex-sorted.
// ---------------------------------------------------------------------------
__device__ __forceinline__ void merge3L(float tv, int idx,
                                        float& b0, float& b1, float& b2,
                                        int& i0, int& i1, int& i2) {
  bool w0 = (tv < b0) || (tv == b0 && idx < i0);
  bool w1 = (tv < b1) || (tv == b1 && idx < i1);
  bool w2 = (tv < b2) || (tv == b2 && idx < i2);
  float ob0 = b0, ob1 = b1;
  int   oi0 = i0, oi1 = i1;
  b0 = w0 ? tv : b0;                    i0 = w0 ? idx : i0;
  b1 = w0 ? ob0 : (w1 ? tv : b1);       i1 = w0 ? oi0 : (w1 ? idx : i1);
  b2 = w1 ? ob1 : (w2 ? tv : b2);       i2 = w1 ? oi1 : (w2 ? idx : i2);
}

// ---------------------------------------------------------------------------
// build_grid: blocks [0,B_) scan the precomputed cell histogram and fill the
// CSR (single pass over pcell/nearnn). Within-cell order arbitrary (atomic
// cursors) — selection is lexicographic.
// Blocks [B_, B_+ZB_): zero acc rows listed in vlist (voxels with cnt>=2,
// collected during prep's atomics — no 2 MB cnt scan). Wave per row,
// lane = channel, 256 B coalesced.
// ---------------------------------------------------------------------------
__global__ __launch_bounds__(256) void build_grid_kernel(
    const float4* __restrict__ nearnn, const int* __restrict__ gcellcnt,
    const int* __restrict__ pcell,
    const int* __restrict__ vcur, const int* __restrict__ vlist,
    int* __restrict__ cell_start, float4* __restrict__ gpts,
    int* __restrict__ gidx, float* __restrict__ acc) {
  __shared__ int lcnt[GCC_];
  __shared__ int lsum[256];
  __shared__ int lcur[GCC_];
  int t = threadIdx.x;
  if (blockIdx.x < (unsigned)B_) {
    int k = blockIdx.x;
    // scan: per-thread 4-elem serial + Hillis-Steele over 256 partials
    int base = t * 4;
    const int* gc = gcellcnt + k * GCC_;
    int c0 = gc[base], c1 = gc[base + 1], c2 = gc[base + 2], c3 = gc[base + 3];
    int s = c0 + c1 + c2 + c3;
    lsum[t] = s;
    __syncthreads();
    for (int off = 1; off < 256; off <<= 1) {
      int v = (t >= off) ? lsum[t - off] : 0;
      __syncthreads();
      lsum[t] += v;
      __syncthreads();
    }
    int ex = lsum[t] - s;                 // exclusive prefix of this thread's 4
    lcnt[base] = ex;
    lcnt[base + 1] = ex + c0;
    lcnt[base + 2] = ex + c0 + c1;
    lcnt[base + 3] = ex + c0 + c1 + c2;
    __syncthreads();
    for (int i = t; i < GCC_; i += 256) {
      cell_start[k * (GCC_ + 1) + i] = lcnt[i];
      lcur[i] = lcnt[i];
    }
    if (t == 255) cell_start[k * (GCC_ + 1) + GCC_] = lsum[255];
    __syncthreads();
    // fill (single pass; cell ids precomputed in prep)
    for (int n = t; n < N_; n += 256) {
      int c = pcell[k * N_ + n];
      if (c >= 0) {
        int p = atomicAdd(&lcur[c], 1);
        gpts[k * N_ + p] = nearnn[k * N_ + n];
        gidx[k * N_ + p] = n;
      }
    }
  } else {
    // ---- zero listed acc rows (cnt>=2 voxels only, ~260 entries) ----
    int nv = *vcur;
    int lane = t & 63;
    int w = (blockIdx.x - B_) * 4 + (t >> 6);   // wave id 0..ZB_*4-1
    for (int e = w; e < nv; e += ZB_ * 4) {
      int flat = vlist[e];                      // k*NYNX_ + v
      acc[(size_t)flat * C_ + lane] = 0.0f;
    }
  }
}

// ---------------------------------------------------------------------------
// Fused NN + scatter.
// Blocks [0, NNB_): exact 3-NN (expanding Chebyshev rings, 8 lanes/far) then
// the SAME octet gathers the three fvT rows (float4, coalesced) and writes
// the interpolated acc row ((i,w) broadcast in-register via shfl, bit-exact).
// NEW: invalid far points (f.w==0, ~50%) contribute nothing — the whole
// octet is uniform in f.w and all shuffles are octet-local, so early-return
// before the ring search (halves NN work).
// Value expr identical to prior scatter: (w0*a + w1*b) + w2*c, contract off.
// Blocks [NNB_, NNB_+4096): near-point scatter, wave/point, lane = channel.
// cnt==1 rows (98%) are plain stores (single writer); cnt>=2 rows atomics.
// ---------------------------------------------------------------------------
__global__ __launch_bounds__(256) void nn_scatter_kernel(
    const float4* __restrict__ far4, const int* __restrict__ cell_start,
    const float4* __restrict__ gpts, const int* __restrict__ gidx,
    const float4* __restrict__ near4, const float* __restrict__ fvT,
    const float* __restrict__ cnt, float* __restrict__ acc) {
#pragma clang fp contract(off)
  int tid = threadIdx.x;
  if (blockIdx.x < (unsigned)NNB_) {
    int q = tid & (LPF_ - 1);
    int g = blockIdx.x * (256 / LPF_) + (tid / LPF_);   // far point id over BN
    int k = g >> 13;                        // /8192
    int m = g & (N_ - 1);

    float4 f = far4[k * N_ + m];
    if (f.w == 0.0f) return;   // invalid far point: octet-uniform, no output

    float sf = (f.x * f.x + f.y * f.y) + f.z * f.z;   // numpy 3-elem order
    float ax = 2.0f * f.x, ay = 2.0f * f.y, az = 2.0f * f.z;
    int fcx = gcell_x(f.x), fcy = gcell_y(f.y);
    const int* cs_ = cell_start + k * (GCC_ + 1);

    float b0 = 1e30f, b1 = 1e30f, b2 = 1e30f;
    int i0 = 0, i1 = 0, i2 = 0;

    for (int r = 0; r < GC_; ++r) {
      int nc = (r == 0) ? 1 : 8 * r;
      for (int i = q; i < nc; i += LPF_) {
        int dx, dy;
        if (r == 0)            { dx = 0;             dy = 0; }
        else if (i < 2*r + 1)  { dx = i - r;         dy = -r; }
        else if (i < 4*r + 2)  { dx = i - (3*r + 1); dy = r; }
        else if (i < 6*r + 1)  { dx = -r;            dy = i - (5*r + 1); }
        else                   { dx = r;             dy = i - 7*r; }
        int cx = fcx + dx, cy = fcy + dy;
        if (cx < 0 || cx >= GC_ || cy < 0 || cy >= GC_) continue;
        int c = cy * GC_ + cx;
        int s = cs_[c], e = cs_[c + 1];
        for (int j = s; j < e; ++j) {
          float4 p = gpts[k * N_ + j];
          int idx = gidx[k * N_ + j];
          float p0 = ax * p.x;                                  // round(ax*px)
          float mm = __builtin_fmaf(az, p.z, __builtin_fmaf(ay, p.y, p0));
          float tv = (sf + p.w) - mm;
          merge3L(tv, idx, b0, b1, b2, i0, i1, i2);
        }
      }
      // octet-shared conservative bound (min of lanes' 3rd-best; 1e30 until
      // some lane holds 3 -> keep expanding, always safe)
      float s2 = b2;
      s2 = fminf(s2, __shfl_xor(s2, 1));
      s2 = fminf(s2, __shfl_xor(s2, 2));
      s2 = fminf(s2, __shfl_xor(s2, 4));
      float rd = (float)r * 1.6f;
      if (rd * rd > s2 + 0.01f) break;
    }

    // octet merge on lane 0 (lexicographic, order-independent)
    int base = tid & ~(LPF_ - 1);
    for (int s = 1; s < LPF_; ++s) {
      float v0 = __shfl(b0, base + s), v1 = __shfl(b1, base + s), v2 = __shfl(b2, base + s);
      int   j0 = __shfl(i0, base + s), j1 = __shfl(i1, base + s), j2 = __shfl(i2, base + s);
      if (q == 0) {
        merge3L(v0, j0, b0, b1, b2, i0, i1, i2);
        merge3L(v1, j1, b0, b1, b2, i0, i1, i2);
        merge3L(v2, j2, b0, b1, b2, i0, i1, i2);
      }
    }
    // weights on lane 0 (exactly as reference), then broadcast bit-exact
    float w0_ = 0.0f, w1_ = 0.0f, w2_ = 0.0f;
    if (q == 0) {
      float r0 = 1.0f / (b0 + 1e-8f);
      float r1 = 1.0f / (b1 + 1e-8f);
      float r2 = 1.0f / (b2 + 1e-8f);
      float rs = (r0 + r1) + r2;
      w0_ = r0 / rs; w1_ = r1 / rs; w2_ = r2 / rs;
    }
    float w0 = __shfl(w0_, base), w1 = __shfl(w1_, base), w2 = __shfl(w2_, base);
    int   j0 = __shfl(i0, base),  j1 = __shfl(i1, base),  j2 = __shfl(i2, base);

    // far-point scatter: octet handles the 64-channel row, lane q owns
    // float4 chunks {2q, 2q+1} (coalesced 256 B per row).
    int v = voxel_of(f.x, f.y, f.w);
    if (v < 0) return;
    float cn = cnt[(size_t)k * NYNX_ + v];
    const float4* r0p = (const float4*)(fvT + ((size_t)(k * N_ + j0)) * C_);
    const float4* r1p = (const float4*)(fvT + ((size_t)(k * N_ + j1)) * C_);
    const float4* r2p = (const float4*)(fvT + ((size_t)(k * N_ + j2)) * C_);
    size_t rowoff = ((size_t)k * NYNX_ + v) * C_;
#pragma unroll
    for (int h = 0; h < 2; ++h) {
      int c4 = q * 2 + h;
      float4 a = r0p[c4], b = r1p[c4], c = r2p[c4];
      float4 val;
      val.x = (w0 * a.x + w1 * b.x) + w2 * c.x;
      val.y = (w0 * a.y + w1 * b.y) + w2 * c.y;
      val.z = (w0 * a.z + w1 * b.z) + w2 * c.z;
      val.w = (w0 * a.w + w1 * b.w) + w2 * c.w;
      if (cn == 1.0f) {
        ((float4*)(acc + rowoff))[c4] = val;
      } else {
        float* p = acc + rowoff + c4 * 4;
        atomicAdd(p + 0, val.x); atomicAdd(p + 1, val.y);
        atomicAdd(p + 2, val.z); atomicAdd(p + 3, val.w);
      }
    }
  } else {
    // ---- near-point scatter: wave per point, lane = channel ----
    int lane = tid & 63;
    int wv = (blockIdx.x - NNB_) * 4 + (tid >> 6);  // 0..BN_-1
    int k = wv >> 13;
    int n = wv & (N_ - 1);
    float4 pt = near4[k * N_ + n];
    int v = voxel_of(pt.x, pt.y, pt.w);
    if (v < 0) return;
    float val = fvT[((size_t)(k * N_ + n)) * C_ + lane];
    size_t rowoff = ((size_t)k * NYNX_ + v) * C_;
    float cn = cnt[(size_t)k * NYNX_ + v];   // wave-uniform
    if (cn == 1.0f) acc[rowoff + lane] = val;
    else            atomicAdd(&acc[rowoff + lane], val);
  }
}

// ---------------------------------------------------------------------------
// Emit out (B,C,NY,NX) from acc/cnt via LDS transpose. Per block: 64 voxels.
// Covers every out element exactly once (fuses the zero-fill + mean divide).
// out is never re-read -> nontemporal stores (keep L2 for acc/cnt).
// ---------------------------------------------------------------------------
__global__ __launch_bounds__(256) void emit_kernel(
    const float* __restrict__ acc, const float* __restrict__ cnt,
    float* __restrict__ out) {
#pragma clang fp contract(off)
  __shared__ float tile[64][65];
  __shared__ float cs[64];
  int t = threadIdx.x;
  int k = blockIdx.y;
  int v0 = blockIdx.x * 64;

  if (t < 64) cs[t] = cnt[(size_t)k * NYNX_ + v0 + t];
  __syncthreads();

  const float4* acc4 = (const float4*)acc;
#pragma unroll
  for (int p = 0; p < 4; ++p) {
    int row = p * 16 + (t >> 4);     // voxel within block
    int f4  = t & 15;                // float4 within the 64-channel row
    float c = cs[row];
    float4 a = make_float4(0.0f, 0.0f, 0.0f, 0.0f);
    if (c > 0.0f) {
      a = acc4[((size_t)k * NYNX_ + v0 + row) * (C_ / 4) + f4];
      a.x /= c; a.y /= c; a.z /= c; a.w /= c;
    }
    tile[f4 * 4 + 0][row] = a.x;
    tile[f4 * 4 + 1][row] = a.y;
    tile[f4 * 4 + 2][row] = a.z;
    tile[f4 * 4 + 3][row] = a.w;
  }
  __syncthreads();

#pragma unroll
  for (int p = 0; p < 4; ++p) {
    int c  = p * 16 + (t >> 4);      // channel
    int xq = t & 15;                 // float4 of voxels
    float4 o = make_float4(tile[c][xq * 4 + 0], tile[c][xq * 4 + 1],
                           tile[c][xq * 4 + 2], tile[c][xq * 4 + 3]);
    store_nt(&((float4*)out)[(((size_t)k * C_ + c) * NYNX_ + v0) / 4 + xq], o);
  }
}

extern "C" void kernel_launch(void* const* d_in, const int* in_sizes, int n_in,
                              void* d_out, int out_size, void* d_ws, size_t ws_size,
                              hipStream_t stream) {
  const float* fv  = (const float*)d_in[0];  // (B,C,H,W)
  const float* pi  = (const float*)d_in[1];  // (B,4,H,W)
  const int*   pm  = (const int*)d_in[2];    // (B,H,W)
  const float* pif = (const float*)d_in[3];  // (B,4,H,W)
  const int*   pmf = (const int*)d_in[4];    // (B,H,W)
  float* out = (float*)d_out;                // (B,C,NY,NX) f32

  // workspace layout (16B aligned): small buffers < 8 MB, acc 134 MB at +8MB.
  // cnt, gcellcnt and vcur are ADJACENT so one memset zeroes all three.
  char* wsb = (char*)d_ws;
  float*  fvT    = (float*)(wsb);                 // 4,194,304
  float*  cnt    = (float*)(wsb + 4194304);       // 2,097,152
  int*    gcell  = (int*)(wsb + 6291456);         // B*1024*4 = 8,192
  int*    vcur   = (int*)(wsb + 6299648);         // 16 (cursor + pad)
  int*    vlist  = (int*)(wsb + 6299664);         // 16384*4 = 65,536
  int*    pcell  = (int*)(wsb + 6365200);         // B*N*4    = 65,536
  float4* near4  = (float4*)(wsb + 6430736);      // 262,144
  float4* far4   = (float4*)(wsb + 6692880);      // 262,144
  float4* nearnn = (float4*)(wsb + 6955024);      // 262,144
  int*    cstart = (int*)(wsb + 7217168);         // 8,320
  int*    gidx   = (int*)(wsb + 7225488);         // 65,536
  float4* gpts   = (float4*)(wsb + 7291024);      // 262,144
  float*  acc    = (float*)(wsb + 8388608);       // 134,217,728

  // one memset covers cnt (2,097,152 B) + gcellcnt (8,192 B) + vcur (16 B)
  hipMemsetAsync(cnt, 0, 2097152 + 8192 + 16, stream);

  prep_kernel<<<320, 256, 0, stream>>>(
      fv, pi, pm, pif, pmf, near4, far4, nearnn, cnt, gcell, pcell,
      vcur, vlist, fvT);
  build_grid_kernel<<<B_ + ZB_, 256, 0, stream>>>(
      nearnn, gcell, pcell, vcur, vlist, cstart, gpts, gidx, acc);
  nn_scatter_kernel<<<NNB_ + B_ * N_ / 4, 256, 0, stream>>>(
      far4, cstart, gpts, gidx, near4, fvT, cnt, acc);
  emit_kernel<<<dim3(NYNX_ / 64, B_), 256, 0, stream>>>(acc, cnt, out);
}

// Round 2
// 179.686 us; speedup vs baseline: 1.1666x; 1.1666x over previous
//
#include <hip/hip_runtime.h>
#include <math.h>

// Problem constants (match the jax reference)
constexpr int B_  = 2;
constexpr int C_  = 64;
constexpr int HW_ = 64 * 128;      // 8192
constexpr int N_  = HW_;           // points per image (near == far == 8192)
constexpr int NX_ = 512;
constexpr int NY_ = 512;
constexpr int NYNX_ = NX_ * NY_;   // 262144
constexpr int GC_  = 32;           // NN search grid is GC x GC cells of 1.6 m
constexpr int GCC_ = GC_ * GC_;    // 1024 cells
constexpr int CAP_ = 48;           // max pts per NN cell (Poisson(4), P(>=48)~1e-40)
constexpr int LPF_ = 8;            // lanes per far point in nn_search
constexpr int BN_  = B_ * N_;      // 16384
constexpr int NNB_ = BN_ / (256 / LPF_);   // 512 NN blocks (32 far pts/block)

// ---------------------------------------------------------------------------
// Shared voxel binning (numpy f32 bitwise). -1 = contributes nothing.
// ---------------------------------------------------------------------------
__device__ __forceinline__ int voxel_of(float x, float y, float w) {
#pragma clang fp contract(off)
  if (w == 0.0f) return -1;
  float qx = (x - 0.0f) / 0.1f;
  float qy = (y - (-25.6f)) / 0.1f;
  int ix = (int)floorf(qx);
  int iy = (int)floorf(qy);
  if (ix < 0 || ix >= NX_ || iy < 0 || iy >= NY_) return -1;
  return iy * NX_ + ix;
}

// NN-grid cell coords (internal only — must be identical in build & search).
__device__ __forceinline__ int gcell_x(float x) {
  int c = (int)floorf(x * 0.625f);          // /1.6
  return min(GC_ - 1, max(0, c));
}
__device__ __forceinline__ int gcell_y(float y) {
  int c = (int)floorf((y + 25.6f) * 0.625f);
  return min(GC_ - 1, max(0, c));
}

// ---------------------------------------------------------------------------
// Fused prep: blocks [0,64) pack+count points AND directly bucket valid near
// points into fixed-capacity NN cells (gpts/gidx at cell*CAP_ + slot, slot
// from the histogram atomicAdd). This replaces the entire CSR build kernel:
// 16384 threads do the fill instead of 512, and no prefix scan is needed.
// Within-cell order is arbitrary (atomic race) — selection is lexicographic,
// so results are bit-exact. The cnt atomics detect the 1->2 transition
// (atomicAdd returns old) and the detecting thread zeroes that 256 B acc row
// inline — safe because all acc SCATTER writes happen in a later kernel.
// Blocks [64,320) transpose fv (B,C,HW) -> fvT (B,HW,C). Halves independent.
// ---------------------------------------------------------------------------
__global__ __launch_bounds__(256) void prep_kernel(
    const float* __restrict__ fv,
    const float* __restrict__ pi, const int* __restrict__ pm,
    const float* __restrict__ pif, const int* __restrict__ pmf,
    float4* __restrict__ near4, float4* __restrict__ far4,
    float* __restrict__ cnt, int* __restrict__ gcellcnt,
    float4* __restrict__ gpts, int* __restrict__ gidx,
    float* __restrict__ acc, float* __restrict__ fvT) {
#pragma clang fp contract(off)
  __shared__ float tile[64][65];
  if (blockIdx.x < 64) {
    // ---- pack + count + bucket fill ----
    int t = blockIdx.x * 256 + threadIdx.x;        // over B_*N_
    int k = t / N_, n = t % N_;
    const float* base  = pi  + (size_t)k * 4 * HW_;
    const float* basef = pif + (size_t)k * 4 * HW_;
    float x = base[n], y = base[HW_ + n], z = base[2 * HW_ + n];
    bool v = pm[k * HW_ + n] > 0;
    near4[t] = make_float4(x, y, z, v ? 1.0f : 0.0f);
    float fx = basef[n], fy = basef[HW_ + n], fz = basef[2 * HW_ + n];
    bool vf = pmf[k * HW_ + n] > 0;
    far4[t] = make_float4(fx, fy, fz, vf ? 1.0f : 0.0f);

    // valid near points -> NN cell bucket (slot from histogram atomic)
    if (v) {
      float sq = (x * x + y * y) + z * z;   // numpy 3-elem sum order
      int c = gcell_y(y) * GC_ + gcell_x(x);
      int p = atomicAdd(&gcellcnt[k * GCC_ + c], 1);
      if (p < CAP_) {
        size_t o = (size_t)(k * GCC_ + c) * CAP_ + p;
        gpts[o] = make_float4(x, y, z, sq);
        gidx[o] = n;
      }
    }

    float4 z4 = make_float4(0.0f, 0.0f, 0.0f, 0.0f);
    int vn = voxel_of(x, y, v ? 1.0f : 0.0f);
    if (vn >= 0) {
      float old = atomicAdd(&cnt[(size_t)k * NYNX_ + vn], 1.0f);
      if (old == 1.0f) {            // exactly one thread sees the 1->2 step
        float4* row = (float4*)(acc + ((size_t)k * NYNX_ + vn) * C_);
#pragma unroll
        for (int i = 0; i < C_ / 4; ++i) row[i] = z4;
      }
    }
    int vfv = voxel_of(fx, fy, vf ? 1.0f : 0.0f);
    if (vfv >= 0) {
      float old2 = atomicAdd(&cnt[(size_t)k * NYNX_ + vfv], 1.0f);
      if (old2 == 1.0f) {
        float4* row = (float4*)(acc + ((size_t)k * NYNX_ + vfv) * C_);
#pragma unroll
        for (int i = 0; i < C_ / 4; ++i) row[i] = z4;
      }
    }
  } else {
    // ---- transpose ----
    int bid = blockIdx.x - 64;          // 0..255
    int k = bid >> 7;                   // /128
    int n0 = (bid & 127) * 64;
    int tx = threadIdx.x & 63, ty = threadIdx.x >> 6;
    for (int c = ty; c < C_; c += 4)
      tile[c][tx] = fv[((size_t)(k * C_ + c)) * HW_ + n0 + tx];
    __syncthreads();
    for (int nn = ty; nn < 64; nn += 4)
      fvT[((size_t)(k * HW_ + n0 + nn)) * C_ + tx] = tile[tx][nn];
  }
}

// ---------------------------------------------------------------------------
// Lexicographic stable top-3 insert on (value, index): lower value wins,
// ties broken by lower index. Order-INDEPENDENT (safe for arbitrary candidate
// order) and equal to jax stable top-k. Invariant: slots lex-sorted.
// ---------------------------------------------------------------------------
__device__ __forceinline__ void merge3L(float tv, int idx,
                                        float& b0, float& b1, float& b2,
                                        int& i0, int& i1, int& i2) {
  bool w0 = (tv < b0) || (tv == b0 && idx < i0);
  bool w1 = (tv < b1) || (tv == b1 && idx < i1);
  bool w2 = (tv < b2) || (tv == b2 && idx < i2);
  float ob0 = b0, ob1 = b1;
  int   oi0 = i0, oi1 = i1;
  b0 = w0 ? tv : b0;                    i0 = w0 ? idx : i0;
  b1 = w0 ? ob0 : (w1 ? tv : b1);       i1 = w0 ? oi0 : (w1 ? idx : i1);
  b2 = w1 ? ob1 : (w2 ? tv : b2);       i2 = w1 ? oi1 : (w2 ? idx : i2);
}

// ---------------------------------------------------------------------------
// Fused NN + scatter.
// Blocks [0, NNB_): exact 3-NN (expanding Chebyshev rings, 8 lanes/far) then
// the SAME octet gathers the three fvT rows (float4, coalesced) and writes
// the interpolated acc row ((i,w) broadcast in-register via shfl, bit-exact).
// Invalid far points (f.w==0, ~50%) contribute nothing — octet-uniform early
// return before the ring search. Candidates come from the fixed-capacity
// cell buckets (cell*CAP_, count in gcellcnt).
// Value expr identical to prior scatter: (w0*a + w1*b) + w2*c, contract off.
// Blocks [NNB_, NNB_+4096): near-point scatter, wave/point, lane = channel.
// cnt==1 rows (98%) are plain stores (single writer); cnt>=2 rows atomics.
// ---------------------------------------------------------------------------
__global__ __launch_bounds__(256) void nn_scatter_kernel(
    const float4* __restrict__ far4, const int* __restrict__ gcellcnt,
    const float4* __restrict__ gpts, const int* __restrict__ gidx,
    const float4* __restrict__ near4, const float* __restrict__ fvT,
    const float* __restrict__ cnt, float* __restrict__ acc) {
#pragma clang fp contract(off)
  int tid = threadIdx.x;
  if (blockIdx.x < (unsigned)NNB_) {
    int q = tid & (LPF_ - 1);
    int g = blockIdx.x * (256 / LPF_) + (tid / LPF_);   // far point id over BN
    int k = g >> 13;                        // /8192
    int m = g & (N_ - 1);

    float4 f = far4[k * N_ + m];
    if (f.w == 0.0f) return;   // invalid far point: octet-uniform, no output

    float sf = (f.x * f.x + f.y * f.y) + f.z * f.z;   // numpy 3-elem order
    float ax = 2.0f * f.x, ay = 2.0f * f.y, az = 2.0f * f.z;
    int fcx = gcell_x(f.x), fcy = gcell_y(f.y);
    const int* gcc_ = gcellcnt + k * GCC_;

    float b0 = 1e30f, b1 = 1e30f, b2 = 1e30f;
    int i0 = 0, i1 = 0, i2 = 0;

    for (int r = 0; r < GC_; ++r) {
      int nc = (r == 0) ? 1 : 8 * r;
      for (int i = q; i < nc; i += LPF_) {
        int dx, dy;
        if (r == 0)            { dx = 0;             dy = 0; }
        else if (i < 2*r + 1)  { dx = i - r;         dy = -r; }
        else if (i < 4*r + 2)  { dx = i - (3*r + 1); dy = r; }
        else if (i < 6*r + 1)  { dx = -r;            dy = i - (5*r + 1); }
        else                   { dx = r;             dy = i - 7*r; }
        int cx = fcx + dx, cy = fcy + dy;
        if (cx < 0 || cx >= GC_ || cy < 0 || cy >= GC_) continue;
        int c = cy * GC_ + cx;
        int e = gcc_[c];
        if (e > CAP_) e = CAP_;
        const float4* gp = gpts + (size_t)(k * GCC_ + c) * CAP_;
        const int*    gi = gidx + (size_t)(k * GCC_ + c) * CAP_;
        for (int j = 0; j < e; ++j) {
          float4 p = gp[j];
          int idx = gi[j];
          float p0 = ax * p.x;                                  // round(ax*px)
          float mm = __builtin_fmaf(az, p.z, __builtin_fmaf(ay, p.y, p0));
          float tv = (sf + p.w) - mm;
          merge3L(tv, idx, b0, b1, b2, i0, i1, i2);
        }
      }
      // octet-shared conservative bound (min of lanes' 3rd-best; 1e30 until
      // some lane holds 3 -> keep expanding, always safe)
      float s2 = b2;
      s2 = fminf(s2, __shfl_xor(s2, 1));
      s2 = fminf(s2, __shfl_xor(s2, 2));
      s2 = fminf(s2, __shfl_xor(s2, 4));
      float rd = (float)r * 1.6f;
      if (rd * rd > s2 + 0.01f) break;
    }

    // octet merge on lane 0 (lexicographic, order-independent)
    int base = tid & ~(LPF_ - 1);
    for (int s = 1; s < LPF_; ++s) {
      float v0 = __shfl(b0, base + s), v1 = __shfl(b1, base + s), v2 = __shfl(b2, base + s);
      int   j0 = __shfl(i0, base + s), j1 = __shfl(i1, base + s), j2 = __shfl(i2, base + s);
      if (q == 0) {
        merge3L(v0, j0, b0, b1, b2, i0, i1, i2);
        merge3L(v1, j1, b0, b1, b2, i0, i1, i2);
        merge3L(v2, j2, b0, b1, b2, i0, i1, i2);
      }
    }
    // weights on lane 0 (exactly as reference), then broadcast bit-exact
    float w0_ = 0.0f, w1_ = 0.0f, w2_ = 0.0f;
    if (q == 0) {
      float r0 = 1.0f / (b0 + 1e-8f);
      float r1 = 1.0f / (b1 + 1e-8f);
      float r2 = 1.0f / (b2 + 1e-8f);
      float rs = (r0 + r1) + r2;
      w0_ = r0 / rs; w1_ = r1 / rs; w2_ = r2 / rs;
    }
    float w0 = __shfl(w0_, base), w1 = __shfl(w1_, base), w2 = __shfl(w2_, base);
    int   j0 = __shfl(i0, base),  j1 = __shfl(i1, base),  j2 = __shfl(i2, base);

    // far-point scatter: octet handles the 64-channel row, lane q owns
    // float4 chunks {2q, 2q+1} (coalesced 256 B per row).
    int v = voxel_of(f.x, f.y, f.w);
    if (v < 0) return;
    float cn = cnt[(size_t)k * NYNX_ + v];
    const float4* r0p = (const float4*)(fvT + ((size_t)(k * N_ + j0)) * C_);
    const float4* r1p = (const float4*)(fvT + ((size_t)(k * N_ + j1)) * C_);
    const float4* r2p = (const float4*)(fvT + ((size_t)(k * N_ + j2)) * C_);
    size_t rowoff = ((size_t)k * NYNX_ + v) * C_;
#pragma unroll
    for (int h = 0; h < 2; ++h) {
      int c4 = q * 2 + h;
      float4 a = r0p[c4], b = r1p[c4], c = r2p[c4];
      float4 val;
      val.x = (w0 * a.x + w1 * b.x) + w2 * c.x;
      val.y = (w0 * a.y + w1 * b.y) + w2 * c.y;
      val.z = (w0 * a.z + w1 * b.z) + w2 * c.z;
      val.w = (w0 * a.w + w1 * b.w) + w2 * c.w;
      if (cn == 1.0f) {
        ((float4*)(acc + rowoff))[c4] = val;
      } else {
        float* p = acc + rowoff + c4 * 4;
        atomicAdd(p + 0, val.x); atomicAdd(p + 1, val.y);
        atomicAdd(p + 2, val.z); atomicAdd(p + 3, val.w);
      }
    }
  } else {
    // ---- near-point scatter: wave per point, lane = channel ----
    int lane = tid & 63;
    int wv = (blockIdx.x - NNB_) * 4 + (tid >> 6);  // 0..BN_-1
    int k = wv >> 13;
    int n = wv & (N_ - 1);
    float4 pt = near4[k * N_ + n];
    int v = voxel_of(pt.x, pt.y, pt.w);
    if (v < 0) return;
    float val = fvT[((size_t)(k * N_ + n)) * C_ + lane];
    size_t rowoff = ((size_t)k * NYNX_ + v) * C_;
    float cn = cnt[(size_t)k * NYNX_ + v];   // wave-uniform
    if (cn == 1.0f) acc[rowoff + lane] = val;
    else            atomicAdd(&acc[rowoff + lane], val);
  }
}

// ---------------------------------------------------------------------------
// Emit out (B,C,NY,NX) from acc/cnt via LDS transpose. Per block: 64 voxels.
// Covers every out element exactly once (fuses the zero-fill + mean divide).
// ---------------------------------------------------------------------------
__global__ __launch_bounds__(256) void emit_kernel(
    const float* __restrict__ acc, const float* __restrict__ cnt,
    float* __restrict__ out) {
#pragma clang fp contract(off)
  __shared__ float tile[64][65];
  __shared__ float cs[64];
  int t = threadIdx.x;
  int k = blockIdx.y;
  int v0 = blockIdx.x * 64;

  if (t < 64) cs[t] = cnt[(size_t)k * NYNX_ + v0 + t];
  __syncthreads();

  const float4* acc4 = (const float4*)acc;
#pragma unroll
  for (int p = 0; p < 4; ++p) {
    int row = p * 16 + (t >> 4);     // voxel within block
    int f4  = t & 15;                // float4 within the 64-channel row
    float c = cs[row];
    float4 a = make_float4(0.0f, 0.0f, 0.0f, 0.0f);
    if (c > 0.0f) {
      a = acc4[((size_t)k * NYNX_ + v0 + row) * (C_ / 4) + f4];
      a.x /= c; a.y /= c; a.z /= c; a.w /= c;
    }
    tile[f4 * 4 + 0][row] = a.x;
    tile[f4 * 4 + 1][row] = a.y;
    tile[f4 * 4 + 2][row] = a.z;
    tile[f4 * 4 + 3][row] = a.w;
  }
  __syncthreads();

#pragma unroll
  for (int p = 0; p < 4; ++p) {
    int c  = p * 16 + (t >> 4);      // channel
    int xq = t & 15;                 // float4 of voxels
    float4 o = make_float4(tile[c][xq * 4 + 0], tile[c][xq * 4 + 1],
                           tile[c][xq * 4 + 2], tile[c][xq * 4 + 3]);
    ((float4*)out)[(((size_t)k * C_ + c) * NYNX_ + v0) / 4 + xq] = o;
  }
}

extern "C" void kernel_launch(void* const* d_in, const int* in_sizes, int n_in,
                              void* d_out, int out_size, void* d_ws, size_t ws_size,
                              hipStream_t stream) {
  const float* fv  = (const float*)d_in[0];  // (B,C,H,W)
  const float* pi  = (const float*)d_in[1];  // (B,4,H,W)
  const int*   pm  = (const int*)d_in[2];    // (B,H,W)
  const float* pif = (const float*)d_in[3];  // (B,4,H,W)
  const int*   pmf = (const int*)d_in[4];    // (B,H,W)
  float* out = (float*)d_out;                // (B,C,NY,NX) f32

  // workspace layout (16B aligned). cnt and gcellcnt are ADJACENT so one
  // memset zeroes both. acc at +16 MB.
  char* wsb = (char*)d_ws;
  float*  fvT    = (float*)(wsb);                 // 4,194,304
  float*  cnt    = (float*)(wsb + 4194304);       // 2,097,152
  int*    gcell  = (int*)(wsb + 6291456);         // B*1024*4 = 8,192
  float4* near4  = (float4*)(wsb + 6299648);      // 262,144
  float4* far4   = (float4*)(wsb + 6561792);      // 262,144
  float4* gpts   = (float4*)(wsb + 6823936);      // B*GCC*CAP*16 = 1,572,864
  int*    gidx   = (int*)(wsb + 8396800);         // B*GCC*CAP*4  =   393,216
  float*  acc    = (float*)(wsb + 16777216);      // 134,217,728

  // one memset covers cnt (2,097,152 B) + gcellcnt (8,192 B)
  hipMemsetAsync(cnt, 0, 2097152 + 8192, stream);

  prep_kernel<<<320, 256, 0, stream>>>(
      fv, pi, pm, pif, pmf, near4, far4, cnt, gcell, gpts, gidx, acc, fvT);
  nn_scatter_kernel<<<NNB_ + B_ * N_ / 4, 256, 0, stream>>>(
      far4, gcell, gpts, gidx, near4, fvT, cnt, acc);
  emit_kernel<<<dim3(NYNX_ / 64, B_), 256, 0, stream>>>(acc, cnt, out);
}